// Round 10
// baseline (266.227 us; speedup 1.0000x reference)
//
#include <hip/hip_runtime.h>

// ---------------------------------------------------------------------------
// MMoE forward, MI355X/gfx950.  Round 10 (R9 retry — LDS budget fixed).
// GEMM1 = gemm8v2: 256x256 tile, 8 waves, 4 phases/K-tile.
//   A (streaming HBM panel): TRI-buffered, prefetched 2 tiles ahead
//     (issue->wait = 7 phases >= ~900cy HBM latency).
//   B (per-XCD L2-resident weights): DOUBLE-buffered, also staged 2 ahead but
//     into the same parity buffer (safe: B-frags are hoisted to registers at
//     tile start; R5-verified pattern).  LDS = 96K + 64K = 160K exactly.
// Ledger (tile u; cA=u%3):
//   start: 8x ds_read B-frags from Bs[u&1] -> regs (lgkm at ph0, sealed by
//          ph0 barrier for all waves before any ph2 stage issue).
//   ph0/1: A-frags; stageA((u+2)%3, h, u+2)  [As[(u+2)%3] last read tile u-1,
//          sealed by its ph3 lgkmcnt(0)+barrier]
//   ph2/3: A-frags; stageB(u&1, h, u+2)
//   ph3:   vmcnt(8) retires exactly tile u+1's 8 loads (FIFO) -> after ph3
//          barrier tile u+1 is in LDS device-wide.  Tail: vmcnt(0).
//   phase = {barrier; lgkmcnt(0); sched_barrier(0); setprio(1); 16 MFMA;
//            setprio(0); barrier}.
// Prologue: stage A0,B0,A1,B1; vmcnt(8); barrier.
// GEMM2/3 = proven 128^2 2-phase kernel; prep/tower = R8 (257.9 µs base).
// ---------------------------------------------------------------------------

typedef unsigned short u16;
typedef unsigned int u32;
typedef __attribute__((ext_vector_type(8))) __bf16 bf16x8;
typedef __attribute__((ext_vector_type(4))) float f32x4;
typedef __attribute__((ext_vector_type(4))) unsigned short u16x4;

#define DEVINL __device__ __forceinline__
#define MFMA16(a, b, c) __builtin_amdgcn_mfma_f32_16x16x32_bf16(a, b, c, 0, 0, 0)

DEVINL u16 f2bf(float f) {            // float -> bf16 bits, round-nearest-even
  union { float f; u32 u; } x; x.f = f;
  u32 u = x.u;
  return (u16)((u + 0x7fffu + ((u >> 16) & 1u)) >> 16);
}
DEVINL float bf2f(u16 h) {
  union { u32 u; float f; } x; x.u = ((u32)h) << 16;
  return x.f;
}
DEVINL void gload16(const u16* g, u16* l) {   // 16B/lane global -> LDS direct
  __builtin_amdgcn_global_load_lds((const __attribute__((address_space(1))) void*)g,
                                   (__attribute__((address_space(3))) void*)l,
                                   16, 0, 0);
}

// ------------------- prep: weight transposes + gather ----------------------
__global__ __launch_bounds__(256)
void prep_kernel(const float* __restrict__ W1, const float* __restrict__ W2,
                 const float* __restrict__ W3,
                 u16* __restrict__ w1t, u16* __restrict__ w2t, u16* __restrict__ w3t,
                 const int* __restrict__ Xd, const float* __restrict__ Xc,
                 const float* __restrict__ lin_emb, const float* __restrict__ deep_emb,
                 const float* __restrict__ gW, const float* __restrict__ gb,
                 u16* __restrict__ ein, float* __restrict__ gates,
                 int rowBase, int Bc)
{
  __shared__ float tbuf[16][65];
  __shared__ float gi[4][32];
  const int bid = blockIdx.x;

  if (bid < 4096) {
    const float* W; u16* WT; int K, N, Kpad, e, kx, ny;
    if (bid < 2816)      { W = W1; WT = w1t; K = 650; N = 512; Kpad = 704;
                           e = bid / 352; const int t = bid % 352; kx = t % 44; ny = t / 44; }
    else if (bid < 3840) { W = W2; WT = w2t; K = 512; N = 256; Kpad = 512;
                           const int t2 = bid - 2816; e = t2 / 128; const int t = t2 % 128; kx = t % 32; ny = t / 32; }
    else                 { W = W3; WT = w3t; K = 256; N = 128; Kpad = 256;
                           const int t3 = bid - 3840; e = t3 / 32; const int t = t3 % 32; kx = t % 16; ny = t / 16; }
    const float* We = W + (size_t)e * K * N;
    u16* Wt = WT + (size_t)e * N * Kpad;
    const int k0 = kx * 16, n0 = ny * 64;
#pragma unroll
    for (int p = 0; p < 4; ++p) {
      const int idx = threadIdx.x + p * 256;
      const int nl = idx & 63, kl = idx >> 6;
      const int gk = k0 + kl;
      tbuf[kl][nl] = (gk < K) ? We[(size_t)gk * N + n0 + nl] : 0.f;
    }
    __syncthreads();
#pragma unroll
    for (int p = 0; p < 4; ++p) {
      const int idx = threadIdx.x + p * 256;
      const int kl = idx & 15, nl = idx >> 4;
      Wt[(size_t)(n0 + nl) * Kpad + k0 + kl] = f2bf(tbuf[kl][nl]);
    }
    return;
  }

  const int gb_ = bid - 4096;
  const int wid = threadIdx.x >> 6, lane = threadIdx.x & 63;
  const int rl = gb_ * 4 + wid;
  const int r = rowBase + rl;
  const int* xd = Xd + (size_t)r * 20;
  u16* er = ein + (size_t)rl * 704;
#pragma unroll
  for (int i = 0; i < 3; ++i) {                 // 20 feat x 8 subchunks = 160
    const int li = i * 64 + lane;
    if (li < 160) {
      const int f = li >> 3, sub = li & 7;
      const int idx = xd[f];
      const float4 v = *(const float4*)&deep_emb[((size_t)f * 100000 + idx) * 32 + sub * 4];
      u16x4 o;
      o.x = f2bf(v.x); o.y = f2bf(v.y); o.z = f2bf(v.z); o.w = f2bf(v.w);
      *(u16x4*)&er[f * 32 + sub * 4] = o;
    }
  }
  if (lane < 10) er[640 + lane] = f2bf(Xc[(size_t)r * 10 + lane]);
  if (lane < 54) er[650 + lane] = 0;
  if (lane < 20) gi[wid][lane] = lin_emb[(size_t)lane * 100000 + xd[lane]];
  if (lane < 10) gi[wid][20 + lane] = Xc[(size_t)r * 10 + lane];
  asm volatile("s_waitcnt lgkmcnt(0)" ::: "memory");
  float logit = 0.f;
  const int t = lane >> 3, ee = lane & 7;
  if (lane < 16) {
    float a = gb[t * 8 + ee];
#pragma unroll
    for (int i = 0; i < 30; ++i) a += gi[wid][i] * gW[(t * 30 + i) * 8 + ee];
    logit = a;
  }
  float mx = logit;
#pragma unroll
  for (int d = 1; d < 8; d <<= 1) mx = fmaxf(mx, __shfl_xor(mx, d));
  float p = expf(logit - mx);
  float sm = p;
#pragma unroll
  for (int d = 1; d < 8; d <<= 1) sm += __shfl_xor(sm, d);
  if (lane < 16) gates[(size_t)rl * 16 + lane] = p / sm;
}

// --------------- 256x256 deep-pipelined GEMM (A tri, B dbl) ----------------
#define AFRAGS(M0, M1)                                                         \
  a00 = *(const bf16x8*)(As0 + (M0) * 1024 + aoff0);                           \
  a01 = *(const bf16x8*)(As0 + (M0) * 1024 + aoff1);                           \
  a10 = *(const bf16x8*)(As0 + (M1) * 1024 + aoff0);                           \
  a11 = *(const bf16x8*)(As0 + (M1) * 1024 + aoff1);

#define SYNC_MFMA(M0, M1)                                                      \
  __builtin_amdgcn_s_barrier();                                                \
  asm volatile("s_waitcnt lgkmcnt(0)" ::: "memory");                           \
  __builtin_amdgcn_sched_barrier(0);                                           \
  __builtin_amdgcn_s_setprio(1);                                               \
  acc[M0][0] = MFMA16(a00, b00, acc[M0][0]);                                   \
  acc[M0][0] = MFMA16(a01, b01, acc[M0][0]);                                   \
  acc[M0][1] = MFMA16(a00, b10, acc[M0][1]);                                   \
  acc[M0][1] = MFMA16(a01, b11, acc[M0][1]);                                   \
  acc[M0][2] = MFMA16(a00, b20, acc[M0][2]);                                   \
  acc[M0][2] = MFMA16(a01, b21, acc[M0][2]);                                   \
  acc[M0][3] = MFMA16(a00, b30, acc[M0][3]);                                   \
  acc[M0][3] = MFMA16(a01, b31, acc[M0][3]);                                   \
  acc[M1][0] = MFMA16(a10, b00, acc[M1][0]);                                   \
  acc[M1][0] = MFMA16(a11, b01, acc[M1][0]);                                   \
  acc[M1][1] = MFMA16(a10, b10, acc[M1][1]);                                   \
  acc[M1][1] = MFMA16(a11, b11, acc[M1][1]);                                   \
  acc[M1][2] = MFMA16(a10, b20, acc[M1][2]);                                   \
  acc[M1][2] = MFMA16(a11, b21, acc[M1][2]);                                   \
  acc[M1][3] = MFMA16(a10, b30, acc[M1][3]);                                   \
  acc[M1][3] = MFMA16(a11, b31, acc[M1][3]);                                   \
  __builtin_amdgcn_s_setprio(0);                                               \
  __builtin_amdgcn_s_barrier();

template<bool RELU, typename CT>
__global__ __launch_bounds__(512, 1)
void gemm8_kernel(const u16* __restrict__ A, size_t sAe,
                  const u16* __restrict__ Bw, size_t sBe,
                  CT* __restrict__ C, size_t sCe, int ldc,
                  const float* __restrict__ bias, int N, int K,
                  int nCol, int nRow)
{
  __shared__ __align__(16) u16 As[3][2][8192];  // A tri-buffer: 96 KB
  __shared__ __align__(16) u16 Bs[2][2][8192];  // B dbl-buffer: 64 KB (=160K)

  const int perE = nCol * nRow;
  const int work = (blockIdx.x & 7) * perE + (blockIdx.x >> 3); // expert/XCD
  const int e = work / perE;
  const int rem = work - e * perE;
  const int mt = rem / nCol, ct = rem - mt * nCol;

  const u16* Ae = A + (size_t)e * sAe;
  const u16* Be = Bw + (size_t)e * sBe;
  const int row0 = mt * 256, col0 = ct * 256;
  const int tid = threadIdx.x, lane = tid & 63, wid = tid >> 6;
  const int wr = wid >> 2, wc = wid & 3;         // 2 wave-rows x 4 wave-cols
  const int KT = K >> 6;

  const int rA = lane >> 3, ch = lane & 7;
  auto stageA = [&](int buf, int h, int kt) {
    const int kb = kt << 6;
#pragma unroll
    for (int j = 0; j < 2; ++j) {
      const int s = j * 8 + wid;                 // segment 0..15
      const int rr = s * 8 + rA;                 // row in half 0..127
      const int gc = ch ^ (rr & 7);
      gload16(Ae + ((size_t)(row0 + h * 128 + rr) * K + kb + (gc << 3)),
              &As[buf][h][s * 512]);
    }
  };
  auto stageB = [&](int buf, int h, int kt) {
    const int kb = kt << 6;
#pragma unroll
    for (int j = 0; j < 2; ++j) {
      const int s = j * 8 + wid;
      const int rr = s * 8 + rA;
      const int gc = ch ^ (rr & 7);
      gload16(Be + ((size_t)(col0 + h * 128 + rr) * K + kb + (gc << 3)),
              &Bs[buf][h][s * 512]);
    }
  };

  // fragment offsets (u16 units): xor row term == lane&7 for all frags since
  // m*16, n*16, (wc&1)*64 are all 0 mod 8.
  const int l15 = lane & 15, l4 = lane >> 4, x0 = lane & 7;
  const int aoff0 = l15 * 64 + ((l4 ^ x0) << 3);          // k-half 0
  const int aoff1 = l15 * 64 + (((4 + l4) ^ x0) << 3);    // k-half 1
  const int bb = (wc & 1) * 64;
  const int boff0 = (bb + l15) * 64 + ((l4 ^ x0) << 3);
  const int boff1 = (bb + l15) * 64 + (((4 + l4) ^ x0) << 3);

  f32x4 acc[8][4];
#pragma unroll
  for (int m = 0; m < 8; ++m)
#pragma unroll
    for (int n = 0; n < 4; ++n) acc[m][n] = {0.f, 0.f, 0.f, 0.f};

  // prologue: stage tiles 0 and 1 (A+B); retire tile 0; barrier.
  stageA(0, 0, 0); stageA(0, 1, 0); stageB(0, 0, 0); stageB(0, 1, 0);
  if (KT > 1) {
    stageA(1, 0, 1); stageA(1, 1, 1); stageB(1, 0, 1); stageB(1, 1, 1);
    asm volatile("s_waitcnt vmcnt(8)" ::: "memory");
  } else {
    asm volatile("s_waitcnt vmcnt(0)" ::: "memory");
  }
  __builtin_amdgcn_s_barrier();

  int cA = 0, nA = 2;                            // cA=u%3, nA=(u+2)%3
  for (int u = 0; u < KT; ++u) {
    const int cB = u & 1;
    const u16* As0 = &As[cA][wr][0];             // this wave's A half
    const u16* Bs0 = &Bs[cB][wc >> 1][0];        // this wave's B half
    bf16x8 a00, a01, a10, a11;
    // B-fragments: read ONCE per tile, held in registers across all 4 phases
    // (frees Bs[cB] for B(u+2) staging from phase 2 on).
    bf16x8 b00 = *(const bf16x8*)(Bs0 + 0 * 1024 + boff0);
    bf16x8 b01 = *(const bf16x8*)(Bs0 + 0 * 1024 + boff1);
    bf16x8 b10 = *(const bf16x8*)(Bs0 + 1 * 1024 + boff0);
    bf16x8 b11 = *(const bf16x8*)(Bs0 + 1 * 1024 + boff1);
    bf16x8 b20 = *(const bf16x8*)(Bs0 + 2 * 1024 + boff0);
    bf16x8 b21 = *(const bf16x8*)(Bs0 + 2 * 1024 + boff1);
    bf16x8 b30 = *(const bf16x8*)(Bs0 + 3 * 1024 + boff0);
    bf16x8 b31 = *(const bf16x8*)(Bs0 + 3 * 1024 + boff1);
    const bool pf = (u + 2 < KT);
    // phase 0
    AFRAGS(0, 1);
    if (pf) stageA(nA, 0, u + 2);
    SYNC_MFMA(0, 1);
    // phase 1
    AFRAGS(2, 3);
    if (pf) stageA(nA, 1, u + 2);
    SYNC_MFMA(2, 3);
    // phase 2
    AFRAGS(4, 5);
    if (pf) stageB(cB, 0, u + 2);                // same-parity overwrite: safe
    SYNC_MFMA(4, 5);
    // phase 3
    AFRAGS(6, 7);
    if (pf) {
      stageB(cB, 1, u + 2);
      asm volatile("s_waitcnt vmcnt(8)" ::: "memory");   // retire tile u+1
    } else {
      asm volatile("s_waitcnt vmcnt(0)" ::: "memory");
    }
    SYNC_MFMA(6, 7);
    cA = (cA == 2) ? 0 : cA + 1;
    nA = (nA == 2) ? 0 : nA + 1;
  }

  // epilogue: C/D layout col=lane&15, row=(lane>>4)*4+reg
  const int rl4 = l4 * 4;
#pragma unroll
  for (int n = 0; n < 4; ++n) {
    const int col = col0 + wc * 64 + n * 16 + l15;
    const float bv = bias[(size_t)e * N + col];
#pragma unroll
    for (int m = 0; m < 8; ++m) {
      const int grow = row0 + wr * 128 + m * 16 + rl4;
      CT* cp = C + (size_t)e * sCe + (size_t)grow * ldc + col;
#pragma unroll
      for (int j = 0; j < 4; ++j) {
        float v = acc[m][n][j] + bv;
        if (RELU) v = fmaxf(v, 0.f);
        if constexpr (sizeof(CT) == 2) cp[(size_t)j * ldc] = (CT)f2bf(v);
        else                           cp[(size_t)j * ldc] = (CT)v;
      }
    }
  }
}

// ------------------------ 128x128 2-phase GEMM -----------------------------
template<bool RELU, typename CT>
__global__ __launch_bounds__(256, 2)
void gemm_kernel(const u16* __restrict__ A, size_t sAe,
                 const u16* __restrict__ Bw, size_t sBe,
                 CT* __restrict__ C, size_t sCe, int ldc,
                 const float* __restrict__ bias, int N, int K,
                 int nCol, int nRow)
{
  __shared__ u16 As[2][8192];
  __shared__ u16 Bs[2][8192];

  const int perE = nCol * nRow;
  const int work = (blockIdx.x & 7) * perE + (blockIdx.x >> 3);
  const int e  = work / perE;
  const int rem = work - e * perE;
  const int mt = rem / nCol;
  const int ct = rem - mt * nCol;

  const u16* Ae = A + (size_t)e * sAe;
  const u16* Be = Bw + (size_t)e * sBe;
  const int row0 = mt * 128;
  const int col0 = ct * 128;
  const int tid = threadIdx.x;
  const int lane = tid & 63;
  const int wid = tid >> 6;
  const int wr = wid >> 1, wc = wid & 1;

  int rw_[4], gch_[4], ldsOff_[4];
#pragma unroll
  for (int i = 0; i < 4; ++i) {
    const int o = (wid * 4 + i) * 1024 + lane * 16;
    rw_[i] = o >> 7;
    const int ch = (o >> 4) & 7;
    gch_[i] = ch ^ (rw_[i] & 7);
    ldsOff_[i] = (wid * 4 + i) * 512;
  }
  const int KT = K >> 6;

  auto stage = [&](int buf, int kt) {
    const int kb = kt << 6;
#pragma unroll
    for (int i = 0; i < 4; ++i) {
      gload16(Ae + ((size_t)(row0 + rw_[i]) * K + kb + (gch_[i] << 3)),
              &As[buf][ldsOff_[i]]);
      gload16(Be + ((size_t)(col0 + rw_[i]) * K + kb + (gch_[i] << 3)),
              &Bs[buf][ldsOff_[i]]);
    }
  };

  f32x4 acc[4][4];
#pragma unroll
  for (int m = 0; m < 4; ++m)
#pragma unroll
    for (int n = 0; n < 4; ++n) acc[m][n] = {0.f, 0.f, 0.f, 0.f};

  stage(0, 0);
  __syncthreads();

  for (int kt = 0; kt < KT; ++kt) {
    const int cur = kt & 1;
    if (kt + 1 < KT) stage(cur ^ 1, kt + 1);
#pragma unroll
    for (int half = 0; half < 2; ++half) {
      const int kp = half * 4 + (lane >> 4);
      bf16x8 af[4], bfr[4];
#pragma unroll
      for (int m = 0; m < 4; ++m) {
        const int rw = wr * 64 + m * 16 + (lane & 15);
        af[m] = *(const bf16x8*)&As[cur][rw * 64 + ((kp ^ (rw & 7)) << 3)];
      }
#pragma unroll
      for (int n = 0; n < 4; ++n) {
        const int rw = wc * 64 + n * 16 + (lane & 15);
        bfr[n] = *(const bf16x8*)&Bs[cur][rw * 64 + ((kp ^ (rw & 7)) << 3)];
      }
      __builtin_amdgcn_s_setprio(1);
#pragma unroll
      for (int m = 0; m < 4; ++m)
#pragma unroll
        for (int n = 0; n < 4; ++n)
          acc[m][n] = MFMA16(af[m], bfr[n], acc[m][n]);
      __builtin_amdgcn_s_setprio(0);
    }
    __syncthreads();
  }

  const int cl = lane & 15;
  const int rl4 = (lane >> 4) * 4;
#pragma unroll
  for (int n = 0; n < 4; ++n) {
    const int col = col0 + wc * 64 + n * 16 + cl;
    const float bv = bias[(size_t)e * N + col];
#pragma unroll
    for (int m = 0; m < 4; ++m) {
      const int grow = row0 + wr * 64 + m * 16 + rl4;
      CT* cp = C + (size_t)e * sCe + (size_t)grow * ldc + col;
#pragma unroll
      for (int j = 0; j < 4; ++j) {
        float v = acc[m][n][j] + bv;
        if (RELU) v = fmaxf(v, 0.f);
        if constexpr (sizeof(CT) == 2) cp[(size_t)j * ldc] = (CT)f2bf(v);
        else                           cp[(size_t)j * ldc] = (CT)v;
      }
    }
  }
}

// ------------------------- combine + task towers ---------------------------
__global__ __launch_bounds__(256)
void tower_kernel(const u16* __restrict__ eo,      // [8][Bc][128] bf16
                  const float* __restrict__ gates, // [Bc][2][8]
                  const float* __restrict__ tW1,   // [2][128][64]
                  const float* __restrict__ tb1, const float* __restrict__ tW2,
                  const float* __restrict__ tb2, float* __restrict__ out,
                  int rowBase, int Bc)
{
  __shared__ u16 w1s[2 * 128 * 64];
  __shared__ float tin[4][2][128];
  for (int i = threadIdx.x; i < 2 * 128 * 64; i += 256) w1s[i] = f2bf(tW1[i]);
  __syncthreads();
  const int wid = threadIdx.x >> 6, lane = threadIdx.x & 63;
  const int stride = gridDim.x * 4;
  for (int it = 0; it < 4; ++it) {
    const int r = blockIdx.x * 4 + wid + it * stride;
    const float* gp = gates + (size_t)r * 16;
    float g[16];
#pragma unroll
    for (int i = 0; i < 16; ++i) g[i] = gp[i];
    float t0a = 0.f, t0b = 0.f, t1a = 0.f, t1b = 0.f;
#pragma unroll
    for (int ee = 0; ee < 8; ++ee) {
      const u32 pv = *(const u32*)(eo + ((size_t)ee * Bc + r) * 128 + lane * 2);
      const float a = bf2f((u16)(pv & 0xffff));
      const float b = bf2f((u16)(pv >> 16));
      t0a += g[ee] * a;      t0b += g[ee] * b;
      t1a += g[8 + ee] * a;  t1b += g[8 + ee] * b;
    }
    tin[wid][0][lane * 2] = t0a; tin[wid][0][lane * 2 + 1] = t0b;
    tin[wid][1][lane * 2] = t1a; tin[wid][1][lane * 2 + 1] = t1b;
    asm volatile("s_waitcnt lgkmcnt(0)" ::: "memory");
#pragma unroll
    for (int t = 0; t < 2; ++t) {
      float acc = tb1[t * 64 + lane];
#pragma unroll 8
      for (int d = 0; d < 128; ++d)
        acc += tin[wid][t][d] * bf2f(w1s[(t * 128 + d) * 64 + lane]);
      acc = fmaxf(acc, 0.f);
      float s = acc * tW2[t * 64 + lane];
#pragma unroll
      for (int dd = 1; dd < 64; dd <<= 1) s += __shfl_xor(s, dd);
      if (lane == 0) out[(size_t)(rowBase + r) * 2 + t] = s + tb2[t];
    }
    asm volatile("s_waitcnt lgkmcnt(0)" ::: "memory");
  }
}

// ------------------------------ launch -------------------------------------
extern "C" void kernel_launch(void* const* d_in, const int* in_sizes, int n_in,
                              void* d_out, int out_size, void* d_ws, size_t ws_size,
                              hipStream_t stream) {
  const int*   X_dis   = (const int*)  d_in[0];
  const float* X_cont  = (const float*)d_in[1];
  const float* lin_emb = (const float*)d_in[2];
  const float* deep_emb= (const float*)d_in[3];
  const float* eW1     = (const float*)d_in[4];
  const float* eb1     = (const float*)d_in[5];
  const float* eW2     = (const float*)d_in[6];
  const float* eb2     = (const float*)d_in[7];
  const float* eW3     = (const float*)d_in[8];
  const float* eb3     = (const float*)d_in[9];
  const float* gW      = (const float*)d_in[10];
  const float* gb      = (const float*)d_in[11];
  const float* tW1     = (const float*)d_in[12];
  const float* tb1     = (const float*)d_in[13];
  const float* tW2     = (const float*)d_in[14];
  const float* tb2     = (const float*)d_in[15];
  float* out = (float*)d_out;

  char* ws = (char*)d_ws;
  u16* w1t = (u16*)(ws + 0);          // 8 x 512 x 704 x 2B
  u16* w2t = (u16*)(ws + 5767168);    // 8 x 256 x 512 x 2B
  u16* w3t = (u16*)(ws + 7864320);    // 8 x 128 x 256 x 2B
  const size_t base = 8388608;

  const int B = 16384;
  int NC = 1;   // per-row: ein 1408 + gates 64 + h1 8192 + h2 4096 = 13760 B
  while (NC < 64 && base + (size_t)(B / NC) * 13760ull > ws_size) NC <<= 1;
  const int Bc = B / NC;

  u16*   ein   = (u16*)  (ws + base);
  float* gates = (float*)(ws + base + (size_t)Bc * 1408);
  u16*   h1    = (u16*)  (ws + base + (size_t)Bc * 1472);
  u16*   h2    = (u16*)  (ws + base + (size_t)Bc * 1472 + (size_t)Bc * 8192);
  u16*   eo    = h1;                  // aliases h1 (dead after GEMM2)

  for (int c = 0; c < NC; ++c) {
    const int rowBase = c * Bc;
    const int nRow = Bc / 128;
    const int nRow8 = Bc / 256;
    prep_kernel<<<4096 + Bc / 4, 256, 0, stream>>>(
        eW1, eW2, eW3, w1t, w2t, w3t,
        X_dis, X_cont, lin_emb, deep_emb, gW, gb, ein, gates, rowBase, Bc);
    gemm8_kernel<true, u16><<<2 * nRow8 * 8, 512, 0, stream>>>(
        ein, 0,                 w1t, (size_t)512 * 704,
        h1, (size_t)Bc * 512, 512, eb1, 512, 704, 2, nRow8);
    gemm_kernel<true, u16><<<2 * nRow * 8, 256, 0, stream>>>(
        h1, (size_t)Bc * 512,   w2t, (size_t)256 * 512,
        h2, (size_t)Bc * 256, 256, eb2, 256, 512, 2, nRow);
    gemm_kernel<false, u16><<<1 * (Bc / 128) * 8, 256, 0, stream>>>(
        h2, (size_t)Bc * 256,   w3t, (size_t)128 * 256,
        eo, (size_t)Bc * 128, 128, eb3, 128, 256, 1, Bc / 128);
    tower_kernel<<<Bc / 16, 256, 0, stream>>>(eo, gates, tW1, tb1, tW2, tb2,
                                              out, rowBase, Bc);
  }
}

// Round 11
// 265.262 us; speedup vs baseline: 1.0036x; 1.0036x over previous
//
#include <hip/hip_runtime.h>

// ---------------------------------------------------------------------------
// MMoE forward, MI355X/gfx950.  Round 11.
// R10 + ONE change: the 16 MFMAs per phase are reordered into two passes of
// 8 INDEPENDENT MFMAs (k-half 0 across all 8 accumulators, then k-half 1).
// R5/R10 both sat at MfmaUtil=23% regardless of prefetch depth because the
// old order issued 8 back-to-back DEPENDENT pairs (same acc twice in a row):
// in-order issue stalls each pair for the MFMA latency, and 1 block/CU has
// no TLP to hide it.  The 128^2 kernel (n-fastest order) never had this.
// Everything else identical to R10 (ledger verified there; passed refcheck).
// ---------------------------------------------------------------------------

typedef unsigned short u16;
typedef unsigned int u32;
typedef __attribute__((ext_vector_type(8))) __bf16 bf16x8;
typedef __attribute__((ext_vector_type(4))) float f32x4;
typedef __attribute__((ext_vector_type(4))) unsigned short u16x4;

#define DEVINL __device__ __forceinline__
#define MFMA16(a, b, c) __builtin_amdgcn_mfma_f32_16x16x32_bf16(a, b, c, 0, 0, 0)

DEVINL u16 f2bf(float f) {            // float -> bf16 bits, round-nearest-even
  union { float f; u32 u; } x; x.f = f;
  u32 u = x.u;
  return (u16)((u + 0x7fffu + ((u >> 16) & 1u)) >> 16);
}
DEVINL float bf2f(u16 h) {
  union { u32 u; float f; } x; x.u = ((u32)h) << 16;
  return x.f;
}
DEVINL void gload16(const u16* g, u16* l) {   // 16B/lane global -> LDS direct
  __builtin_amdgcn_global_load_lds((const __attribute__((address_space(1))) void*)g,
                                   (__attribute__((address_space(3))) void*)l,
                                   16, 0, 0);
}

// ------------------- prep: weight transposes + gather ----------------------
__global__ __launch_bounds__(256)
void prep_kernel(const float* __restrict__ W1, const float* __restrict__ W2,
                 const float* __restrict__ W3,
                 u16* __restrict__ w1t, u16* __restrict__ w2t, u16* __restrict__ w3t,
                 const int* __restrict__ Xd, const float* __restrict__ Xc,
                 const float* __restrict__ lin_emb, const float* __restrict__ deep_emb,
                 const float* __restrict__ gW, const float* __restrict__ gb,
                 u16* __restrict__ ein, float* __restrict__ gates,
                 int rowBase, int Bc)
{
  __shared__ float tbuf[16][65];
  __shared__ float gi[4][32];
  const int bid = blockIdx.x;

  if (bid < 4096) {
    const float* W; u16* WT; int K, N, Kpad, e, kx, ny;
    if (bid < 2816)      { W = W1; WT = w1t; K = 650; N = 512; Kpad = 704;
                           e = bid / 352; const int t = bid % 352; kx = t % 44; ny = t / 44; }
    else if (bid < 3840) { W = W2; WT = w2t; K = 512; N = 256; Kpad = 512;
                           const int t2 = bid - 2816; e = t2 / 128; const int t = t2 % 128; kx = t % 32; ny = t / 32; }
    else                 { W = W3; WT = w3t; K = 256; N = 128; Kpad = 256;
                           const int t3 = bid - 3840; e = t3 / 32; const int t = t3 % 32; kx = t % 16; ny = t / 16; }
    const float* We = W + (size_t)e * K * N;
    u16* Wt = WT + (size_t)e * N * Kpad;
    const int k0 = kx * 16, n0 = ny * 64;
#pragma unroll
    for (int p = 0; p < 4; ++p) {
      const int idx = threadIdx.x + p * 256;
      const int nl = idx & 63, kl = idx >> 6;
      const int gk = k0 + kl;
      tbuf[kl][nl] = (gk < K) ? We[(size_t)gk * N + n0 + nl] : 0.f;
    }
    __syncthreads();
#pragma unroll
    for (int p = 0; p < 4; ++p) {
      const int idx = threadIdx.x + p * 256;
      const int kl = idx & 15, nl = idx >> 4;
      Wt[(size_t)(n0 + nl) * Kpad + k0 + kl] = f2bf(tbuf[kl][nl]);
    }
    return;
  }

  const int gb_ = bid - 4096;
  const int wid = threadIdx.x >> 6, lane = threadIdx.x & 63;
  const int rl = gb_ * 4 + wid;
  const int r = rowBase + rl;
  const int* xd = Xd + (size_t)r * 20;
  u16* er = ein + (size_t)rl * 704;
#pragma unroll
  for (int i = 0; i < 3; ++i) {                 // 20 feat x 8 subchunks = 160
    const int li = i * 64 + lane;
    if (li < 160) {
      const int f = li >> 3, sub = li & 7;
      const int idx = xd[f];
      const float4 v = *(const float4*)&deep_emb[((size_t)f * 100000 + idx) * 32 + sub * 4];
      u16x4 o;
      o.x = f2bf(v.x); o.y = f2bf(v.y); o.z = f2bf(v.z); o.w = f2bf(v.w);
      *(u16x4*)&er[f * 32 + sub * 4] = o;
    }
  }
  if (lane < 10) er[640 + lane] = f2bf(Xc[(size_t)r * 10 + lane]);
  if (lane < 54) er[650 + lane] = 0;
  if (lane < 20) gi[wid][lane] = lin_emb[(size_t)lane * 100000 + xd[lane]];
  if (lane < 10) gi[wid][20 + lane] = Xc[(size_t)r * 10 + lane];
  asm volatile("s_waitcnt lgkmcnt(0)" ::: "memory");
  float logit = 0.f;
  const int t = lane >> 3, ee = lane & 7;
  if (lane < 16) {
    float a = gb[t * 8 + ee];
#pragma unroll
    for (int i = 0; i < 30; ++i) a += gi[wid][i] * gW[(t * 30 + i) * 8 + ee];
    logit = a;
  }
  float mx = logit;
#pragma unroll
  for (int d = 1; d < 8; d <<= 1) mx = fmaxf(mx, __shfl_xor(mx, d));
  float p = expf(logit - mx);
  float sm = p;
#pragma unroll
  for (int d = 1; d < 8; d <<= 1) sm += __shfl_xor(sm, d);
  if (lane < 16) gates[(size_t)rl * 16 + lane] = p / sm;
}

// --------------- 256x256 deep-pipelined GEMM (A tri, B dbl) ----------------
#define AFRAGS(M0, M1)                                                         \
  a00 = *(const bf16x8*)(As0 + (M0) * 1024 + aoff0);                           \
  a01 = *(const bf16x8*)(As0 + (M0) * 1024 + aoff1);                           \
  a10 = *(const bf16x8*)(As0 + (M1) * 1024 + aoff0);                           \
  a11 = *(const bf16x8*)(As0 + (M1) * 1024 + aoff1);

// 16 MFMAs as two passes of 8 INDEPENDENT ops (reuse distance 8, no
// back-to-back dependent pairs).
#define SYNC_MFMA(M0, M1)                                                      \
  __builtin_amdgcn_s_barrier();                                                \
  asm volatile("s_waitcnt lgkmcnt(0)" ::: "memory");                           \
  __builtin_amdgcn_sched_barrier(0);                                           \
  __builtin_amdgcn_s_setprio(1);                                               \
  acc[M0][0] = MFMA16(a00, b00, acc[M0][0]);                                   \
  acc[M0][1] = MFMA16(a00, b10, acc[M0][1]);                                   \
  acc[M0][2] = MFMA16(a00, b20, acc[M0][2]);                                   \
  acc[M0][3] = MFMA16(a00, b30, acc[M0][3]);                                   \
  acc[M1][0] = MFMA16(a10, b00, acc[M1][0]);                                   \
  acc[M1][1] = MFMA16(a10, b10, acc[M1][1]);                                   \
  acc[M1][2] = MFMA16(a10, b20, acc[M1][2]);                                   \
  acc[M1][3] = MFMA16(a10, b30, acc[M1][3]);                                   \
  acc[M0][0] = MFMA16(a01, b01, acc[M0][0]);                                   \
  acc[M0][1] = MFMA16(a01, b11, acc[M0][1]);                                   \
  acc[M0][2] = MFMA16(a01, b21, acc[M0][2]);                                   \
  acc[M0][3] = MFMA16(a01, b31, acc[M0][3]);                                   \
  acc[M1][0] = MFMA16(a11, b01, acc[M1][0]);                                   \
  acc[M1][1] = MFMA16(a11, b11, acc[M1][1]);                                   \
  acc[M1][2] = MFMA16(a11, b21, acc[M1][2]);                                   \
  acc[M1][3] = MFMA16(a11, b31, acc[M1][3]);                                   \
  __builtin_amdgcn_s_setprio(0);                                               \
  __builtin_amdgcn_s_barrier();

template<bool RELU, typename CT>
__global__ __launch_bounds__(512, 1)
void gemm8_kernel(const u16* __restrict__ A, size_t sAe,
                  const u16* __restrict__ Bw, size_t sBe,
                  CT* __restrict__ C, size_t sCe, int ldc,
                  const float* __restrict__ bias, int N, int K,
                  int nCol, int nRow)
{
  __shared__ __align__(16) u16 As[3][2][8192];  // A tri-buffer: 96 KB
  __shared__ __align__(16) u16 Bs[2][2][8192];  // B dbl-buffer: 64 KB (=160K)

  const int perE = nCol * nRow;
  const int work = (blockIdx.x & 7) * perE + (blockIdx.x >> 3); // expert/XCD
  const int e = work / perE;
  const int rem = work - e * perE;
  const int mt = rem / nCol, ct = rem - mt * nCol;

  const u16* Ae = A + (size_t)e * sAe;
  const u16* Be = Bw + (size_t)e * sBe;
  const int row0 = mt * 256, col0 = ct * 256;
  const int tid = threadIdx.x, lane = tid & 63, wid = tid >> 6;
  const int wr = wid >> 2, wc = wid & 3;         // 2 wave-rows x 4 wave-cols
  const int KT = K >> 6;

  const int rA = lane >> 3, ch = lane & 7;
  auto stageA = [&](int buf, int h, int kt) {
    const int kb = kt << 6;
#pragma unroll
    for (int j = 0; j < 2; ++j) {
      const int s = j * 8 + wid;                 // segment 0..15
      const int rr = s * 8 + rA;                 // row in half 0..127
      const int gc = ch ^ (rr & 7);
      gload16(Ae + ((size_t)(row0 + h * 128 + rr) * K + kb + (gc << 3)),
              &As[buf][h][s * 512]);
    }
  };
  auto stageB = [&](int buf, int h, int kt) {
    const int kb = kt << 6;
#pragma unroll
    for (int j = 0; j < 2; ++j) {
      const int s = j * 8 + wid;
      const int rr = s * 8 + rA;
      const int gc = ch ^ (rr & 7);
      gload16(Be + ((size_t)(col0 + h * 128 + rr) * K + kb + (gc << 3)),
              &Bs[buf][h][s * 512]);
    }
  };

  // fragment offsets (u16 units): xor row term == lane&7 for all frags since
  // m*16, n*16, (wc&1)*64 are all 0 mod 8.
  const int l15 = lane & 15, l4 = lane >> 4, x0 = lane & 7;
  const int aoff0 = l15 * 64 + ((l4 ^ x0) << 3);          // k-half 0
  const int aoff1 = l15 * 64 + (((4 + l4) ^ x0) << 3);    // k-half 1
  const int bb = (wc & 1) * 64;
  const int boff0 = (bb + l15) * 64 + ((l4 ^ x0) << 3);
  const int boff1 = (bb + l15) * 64 + (((4 + l4) ^ x0) << 3);

  f32x4 acc[8][4];
#pragma unroll
  for (int m = 0; m < 8; ++m)
#pragma unroll
    for (int n = 0; n < 4; ++n) acc[m][n] = {0.f, 0.f, 0.f, 0.f};

  // prologue: stage tiles 0 and 1 (A+B); retire tile 0; barrier.
  stageA(0, 0, 0); stageA(0, 1, 0); stageB(0, 0, 0); stageB(0, 1, 0);
  if (KT > 1) {
    stageA(1, 0, 1); stageA(1, 1, 1); stageB(1, 0, 1); stageB(1, 1, 1);
    asm volatile("s_waitcnt vmcnt(8)" ::: "memory");
  } else {
    asm volatile("s_waitcnt vmcnt(0)" ::: "memory");
  }
  __builtin_amdgcn_s_barrier();

  int cA = 0, nA = 2;                            // cA=u%3, nA=(u+2)%3
  for (int u = 0; u < KT; ++u) {
    const int cB = u & 1;
    const u16* As0 = &As[cA][wr][0];             // this wave's A half
    const u16* Bs0 = &Bs[cB][wc >> 1][0];        // this wave's B half
    bf16x8 a00, a01, a10, a11;
    // B-fragments: read ONCE per tile, held in registers across all 4 phases
    // (frees Bs[cB] for B(u+2) staging from phase 2 on).
    bf16x8 b00 = *(const bf16x8*)(Bs0 + 0 * 1024 + boff0);
    bf16x8 b01 = *(const bf16x8*)(Bs0 + 0 * 1024 + boff1);
    bf16x8 b10 = *(const bf16x8*)(Bs0 + 1 * 1024 + boff0);
    bf16x8 b11 = *(const bf16x8*)(Bs0 + 1 * 1024 + boff1);
    bf16x8 b20 = *(const bf16x8*)(Bs0 + 2 * 1024 + boff0);
    bf16x8 b21 = *(const bf16x8*)(Bs0 + 2 * 1024 + boff1);
    bf16x8 b30 = *(const bf16x8*)(Bs0 + 3 * 1024 + boff0);
    bf16x8 b31 = *(const bf16x8*)(Bs0 + 3 * 1024 + boff1);
    const bool pf = (u + 2 < KT);
    // phase 0
    AFRAGS(0, 1);
    if (pf) stageA(nA, 0, u + 2);
    SYNC_MFMA(0, 1);
    // phase 1
    AFRAGS(2, 3);
    if (pf) stageA(nA, 1, u + 2);
    SYNC_MFMA(2, 3);
    // phase 2
    AFRAGS(4, 5);
    if (pf) stageB(cB, 0, u + 2);                // same-parity overwrite: safe
    SYNC_MFMA(4, 5);
    // phase 3
    AFRAGS(6, 7);
    if (pf) {
      stageB(cB, 1, u + 2);
      asm volatile("s_waitcnt vmcnt(8)" ::: "memory");   // retire tile u+1
    } else {
      asm volatile("s_waitcnt vmcnt(0)" ::: "memory");
    }
    SYNC_MFMA(6, 7);
    cA = (cA == 2) ? 0 : cA + 1;
    nA = (nA == 2) ? 0 : nA + 1;
  }

  // epilogue: C/D layout col=lane&15, row=(lane>>4)*4+reg
  const int rl4 = l4 * 4;
#pragma unroll
  for (int n = 0; n < 4; ++n) {
    const int col = col0 + wc * 64 + n * 16 + l15;
    const float bv = bias[(size_t)e * N + col];
#pragma unroll
    for (int m = 0; m < 8; ++m) {
      const int grow = row0 + wr * 128 + m * 16 + rl4;
      CT* cp = C + (size_t)e * sCe + (size_t)grow * ldc + col;
#pragma unroll
      for (int j = 0; j < 4; ++j) {
        float v = acc[m][n][j] + bv;
        if (RELU) v = fmaxf(v, 0.f);
        if constexpr (sizeof(CT) == 2) cp[(size_t)j * ldc] = (CT)f2bf(v);
        else                           cp[(size_t)j * ldc] = (CT)v;
      }
    }
  }
}

// ------------------------ 128x128 2-phase GEMM -----------------------------
template<bool RELU, typename CT>
__global__ __launch_bounds__(256, 2)
void gemm_kernel(const u16* __restrict__ A, size_t sAe,
                 const u16* __restrict__ Bw, size_t sBe,
                 CT* __restrict__ C, size_t sCe, int ldc,
                 const float* __restrict__ bias, int N, int K,
                 int nCol, int nRow)
{
  __shared__ u16 As[2][8192];
  __shared__ u16 Bs[2][8192];

  const int perE = nCol * nRow;
  const int work = (blockIdx.x & 7) * perE + (blockIdx.x >> 3);
  const int e  = work / perE;
  const int rem = work - e * perE;
  const int mt = rem / nCol;
  const int ct = rem - mt * nCol;

  const u16* Ae = A + (size_t)e * sAe;
  const u16* Be = Bw + (size_t)e * sBe;
  const int row0 = mt * 128;
  const int col0 = ct * 128;
  const int tid = threadIdx.x;
  const int lane = tid & 63;
  const int wid = tid >> 6;
  const int wr = wid >> 1, wc = wid & 1;

  int rw_[4], gch_[4], ldsOff_[4];
#pragma unroll
  for (int i = 0; i < 4; ++i) {
    const int o = (wid * 4 + i) * 1024 + lane * 16;
    rw_[i] = o >> 7;
    const int ch = (o >> 4) & 7;
    gch_[i] = ch ^ (rw_[i] & 7);
    ldsOff_[i] = (wid * 4 + i) * 512;
  }
  const int KT = K >> 6;

  auto stage = [&](int buf, int kt) {
    const int kb = kt << 6;
#pragma unroll
    for (int i = 0; i < 4; ++i) {
      gload16(Ae + ((size_t)(row0 + rw_[i]) * K + kb + (gch_[i] << 3)),
              &As[buf][ldsOff_[i]]);
      gload16(Be + ((size_t)(col0 + rw_[i]) * K + kb + (gch_[i] << 3)),
              &Bs[buf][ldsOff_[i]]);
    }
  };

  f32x4 acc[4][4];
#pragma unroll
  for (int m = 0; m < 4; ++m)
#pragma unroll
    for (int n = 0; n < 4; ++n) acc[m][n] = {0.f, 0.f, 0.f, 0.f};

  stage(0, 0);
  __syncthreads();

  for (int kt = 0; kt < KT; ++kt) {
    const int cur = kt & 1;
    if (kt + 1 < KT) stage(cur ^ 1, kt + 1);
#pragma unroll
    for (int half = 0; half < 2; ++half) {
      const int kp = half * 4 + (lane >> 4);
      bf16x8 af[4], bfr[4];
#pragma unroll
      for (int m = 0; m < 4; ++m) {
        const int rw = wr * 64 + m * 16 + (lane & 15);
        af[m] = *(const bf16x8*)&As[cur][rw * 64 + ((kp ^ (rw & 7)) << 3)];
      }
#pragma unroll
      for (int n = 0; n < 4; ++n) {
        const int rw = wc * 64 + n * 16 + (lane & 15);
        bfr[n] = *(const bf16x8*)&Bs[cur][rw * 64 + ((kp ^ (rw & 7)) << 3)];
      }
      __builtin_amdgcn_s_setprio(1);
#pragma unroll
      for (int m = 0; m < 4; ++m)
#pragma unroll
        for (int n = 0; n < 4; ++n)
          acc[m][n] = MFMA16(af[m], bfr[n], acc[m][n]);
      __builtin_amdgcn_s_setprio(0);
    }
    __syncthreads();
  }

  const int cl = lane & 15;
  const int rl4 = (lane >> 4) * 4;
#pragma unroll
  for (int n = 0; n < 4; ++n) {
    const int col = col0 + wc * 64 + n * 16 + cl;
    const float bv = bias[(size_t)e * N + col];
#pragma unroll
    for (int m = 0; m < 4; ++m) {
      const int grow = row0 + wr * 64 + m * 16 + rl4;
      CT* cp = C + (size_t)e * sCe + (size_t)grow * ldc + col;
#pragma unroll
      for (int j = 0; j < 4; ++j) {
        float v = acc[m][n][j] + bv;
        if (RELU) v = fmaxf(v, 0.f);
        if constexpr (sizeof(CT) == 2) cp[(size_t)j * ldc] = (CT)f2bf(v);
        else                           cp[(size_t)j * ldc] = (CT)v;
      }
    }
  }
}

// ------------------------- combine + task towers ---------------------------
__global__ __launch_bounds__(256)
void tower_kernel(const u16* __restrict__ eo,      // [8][Bc][128] bf16
                  const float* __restrict__ gates, // [Bc][2][8]
                  const float* __restrict__ tW1,   // [2][128][64]
                  const float* __restrict__ tb1, const float* __restrict__ tW2,
                  const float* __restrict__ tb2, float* __restrict__ out,
                  int rowBase, int Bc)
{
  __shared__ u16 w1s[2 * 128 * 64];
  __shared__ float tin[4][2][128];
  for (int i = threadIdx.x; i < 2 * 128 * 64; i += 256) w1s[i] = f2bf(tW1[i]);
  __syncthreads();
  const int wid = threadIdx.x >> 6, lane = threadIdx.x & 63;
  const int stride = gridDim.x * 4;
  for (int it = 0; it < 4; ++it) {
    const int r = blockIdx.x * 4 + wid + it * stride;
    const float* gp = gates + (size_t)r * 16;
    float g[16];
#pragma unroll
    for (int i = 0; i < 16; ++i) g[i] = gp[i];
    float t0a = 0.f, t0b = 0.f, t1a = 0.f, t1b = 0.f;
#pragma unroll
    for (int ee = 0; ee < 8; ++ee) {
      const u32 pv = *(const u32*)(eo + ((size_t)ee * Bc + r) * 128 + lane * 2);
      const float a = bf2f((u16)(pv & 0xffff));
      const float b = bf2f((u16)(pv >> 16));
      t0a += g[ee] * a;      t0b += g[ee] * b;
      t1a += g[8 + ee] * a;  t1b += g[8 + ee] * b;
    }
    tin[wid][0][lane * 2] = t0a; tin[wid][0][lane * 2 + 1] = t0b;
    tin[wid][1][lane * 2] = t1a; tin[wid][1][lane * 2 + 1] = t1b;
    asm volatile("s_waitcnt lgkmcnt(0)" ::: "memory");
#pragma unroll
    for (int t = 0; t < 2; ++t) {
      float acc = tb1[t * 64 + lane];
#pragma unroll 8
      for (int d = 0; d < 128; ++d)
        acc += tin[wid][t][d] * bf2f(w1s[(t * 128 + d) * 64 + lane]);
      acc = fmaxf(acc, 0.f);
      float s = acc * tW2[t * 64 + lane];
#pragma unroll
      for (int dd = 1; dd < 64; dd <<= 1) s += __shfl_xor(s, dd);
      if (lane == 0) out[(size_t)(rowBase + r) * 2 + t] = s + tb2[t];
    }
    asm volatile("s_waitcnt lgkmcnt(0)" ::: "memory");
  }
}

// ------------------------------ launch -------------------------------------
extern "C" void kernel_launch(void* const* d_in, const int* in_sizes, int n_in,
                              void* d_out, int out_size, void* d_ws, size_t ws_size,
                              hipStream_t stream) {
  const int*   X_dis   = (const int*)  d_in[0];
  const float* X_cont  = (const float*)d_in[1];
  const float* lin_emb = (const float*)d_in[2];
  const float* deep_emb= (const float*)d_in[3];
  const float* eW1     = (const float*)d_in[4];
  const float* eb1     = (const float*)d_in[5];
  const float* eW2     = (const float*)d_in[6];
  const float* eb2     = (const float*)d_in[7];
  const float* eW3     = (const float*)d_in[8];
  const float* eb3     = (const float*)d_in[9];
  const float* gW      = (const float*)d_in[10];
  const float* gb      = (const float*)d_in[11];
  const float* tW1     = (const float*)d_in[12];
  const float* tb1     = (const float*)d_in[13];
  const float* tW2     = (const float*)d_in[14];
  const float* tb2     = (const float*)d_in[15];
  float* out = (float*)d_out;

  char* ws = (char*)d_ws;
  u16* w1t = (u16*)(ws + 0);          // 8 x 512 x 704 x 2B
  u16* w2t = (u16*)(ws + 5767168);    // 8 x 256 x 512 x 2B
  u16* w3t = (u16*)(ws + 7864320);    // 8 x 128 x 256 x 2B
  const size_t base = 8388608;

  const int B = 16384;
  int NC = 1;   // per-row: ein 1408 + gates 64 + h1 8192 + h2 4096 = 13760 B
  while (NC < 64 && base + (size_t)(B / NC) * 13760ull > ws_size) NC <<= 1;
  const int Bc = B / NC;

  u16*   ein   = (u16*)  (ws + base);
  float* gates = (float*)(ws + base + (size_t)Bc * 1408);
  u16*   h1    = (u16*)  (ws + base + (size_t)Bc * 1472);
  u16*   h2    = (u16*)  (ws + base + (size_t)Bc * 1472 + (size_t)Bc * 8192);
  u16*   eo    = h1;                  // aliases h1 (dead after GEMM2)

  for (int c = 0; c < NC; ++c) {
    const int rowBase = c * Bc;
    const int nRow = Bc / 128;
    const int nRow8 = Bc / 256;
    prep_kernel<<<4096 + Bc / 4, 256, 0, stream>>>(
        eW1, eW2, eW3, w1t, w2t, w3t,
        X_dis, X_cont, lin_emb, deep_emb, gW, gb, ein, gates, rowBase, Bc);
    gemm8_kernel<true, u16><<<2 * nRow8 * 8, 512, 0, stream>>>(
        ein, 0,                 w1t, (size_t)512 * 704,
        h1, (size_t)Bc * 512, 512, eb1, 512, 704, 2, nRow8);
    gemm_kernel<true, u16><<<2 * nRow * 8, 256, 0, stream>>>(
        h1, (size_t)Bc * 512,   w2t, (size_t)256 * 512,
        h2, (size_t)Bc * 256, 256, eb2, 256, 512, 2, nRow);
    gemm_kernel<false, u16><<<1 * (Bc / 128) * 8, 256, 0, stream>>>(
        h2, (size_t)Bc * 256,   w3t, (size_t)128 * 256,
        eo, (size_t)Bc * 128, 128, eb3, 128, 256, 1, Bc / 128);
    tower_kernel<<<Bc / 16, 256, 0, stream>>>(eo, gates, tW1, tb1, tW2, tb2,
                                              out, rowBase, Bc);
  }
}

// Round 12
// 255.927 us; speedup vs baseline: 1.0402x; 1.0365x over previous
//
#include <hip/hip_runtime.h>

// ---------------------------------------------------------------------------
// MMoE forward, MI355X/gfx950.  Round 12 — revert to R8 (best measured:
// 257.9 µs).  Six rounds of deep-pipeline variants (R2/R4/R5/R9/R10/R11) all
// measured worse (MfmaUtil pinned ~23% = the m141/m232 pinned-schedule
// failure mode); tail fusion (R6/R7) measured worse.  This is the proven
// configuration: prep co-launch (transposes ∥ gather), 128x128 2-phase GEMMs
// with expert-per-XCD swizzle, bf16 eo, combine+towers in tower_kernel.
// ---------------------------------------------------------------------------

typedef unsigned short u16;
typedef unsigned int u32;
typedef __attribute__((ext_vector_type(8))) __bf16 bf16x8;
typedef __attribute__((ext_vector_type(4))) float f32x4;
typedef __attribute__((ext_vector_type(4))) unsigned short u16x4;

#define DEVINL __device__ __forceinline__
#define MFMA16(a, b, c) __builtin_amdgcn_mfma_f32_16x16x32_bf16(a, b, c, 0, 0, 0)

DEVINL u16 f2bf(float f) {            // float -> bf16 bits, round-nearest-even
  union { float f; u32 u; } x; x.f = f;
  u32 u = x.u;
  return (u16)((u + 0x7fffu + ((u >> 16) & 1u)) >> 16);
}
DEVINL float bf2f(u16 h) {
  union { u32 u; float f; } x; x.u = ((u32)h) << 16;
  return x.f;
}
DEVINL void gload16(const u16* g, u16* l) {   // 16B/lane global -> LDS direct
  __builtin_amdgcn_global_load_lds((const __attribute__((address_space(1))) void*)g,
                                   (__attribute__((address_space(3))) void*)l,
                                   16, 0, 0);
}

// ------------------- prep: weight transposes + gather ----------------------
// blocks [0,2816): W1 -> w1t   (e=bid/352; 44 k-tiles x 8 n-tiles)
// blocks [2816,3840): W2 -> w2t (e=(bid-2816)/128; 32 x 4)
// blocks [3840,4096): W3 -> w3t (e=(bid-3840)/32; 16 x 2)
// blocks [4096,4096+Bc/4): gather (4 rows/block)
__global__ __launch_bounds__(256)
void prep_kernel(const float* __restrict__ W1, const float* __restrict__ W2,
                 const float* __restrict__ W3,
                 u16* __restrict__ w1t, u16* __restrict__ w2t, u16* __restrict__ w3t,
                 const int* __restrict__ Xd, const float* __restrict__ Xc,
                 const float* __restrict__ lin_emb, const float* __restrict__ deep_emb,
                 const float* __restrict__ gW, const float* __restrict__ gb,
                 u16* __restrict__ ein, float* __restrict__ gates,
                 int rowBase, int Bc)
{
  __shared__ float tbuf[16][65];
  __shared__ float gi[4][32];
  const int bid = blockIdx.x;

  if (bid < 4096) {
    // ---- transpose part: W [E][K][N] f32 -> WT [E][N][Kpad] bf16 ----
    const float* W; u16* WT; int K, N, Kpad, e, kx, ny;
    if (bid < 2816)      { W = W1; WT = w1t; K = 650; N = 512; Kpad = 704;
                           e = bid / 352; const int t = bid % 352; kx = t % 44; ny = t / 44; }
    else if (bid < 3840) { W = W2; WT = w2t; K = 512; N = 256; Kpad = 512;
                           const int t2 = bid - 2816; e = t2 / 128; const int t = t2 % 128; kx = t % 32; ny = t / 32; }
    else                 { W = W3; WT = w3t; K = 256; N = 128; Kpad = 256;
                           const int t3 = bid - 3840; e = t3 / 32; const int t = t3 % 32; kx = t % 16; ny = t / 16; }
    const float* We = W + (size_t)e * K * N;
    u16* Wt = WT + (size_t)e * N * Kpad;
    const int k0 = kx * 16, n0 = ny * 64;
#pragma unroll
    for (int p = 0; p < 4; ++p) {
      const int idx = threadIdx.x + p * 256;
      const int nl = idx & 63, kl = idx >> 6;
      const int gk = k0 + kl;
      tbuf[kl][nl] = (gk < K) ? We[(size_t)gk * N + n0 + nl] : 0.f;
    }
    __syncthreads();
#pragma unroll
    for (int p = 0; p < 4; ++p) {
      const int idx = threadIdx.x + p * 256;
      const int kl = idx & 15, nl = idx >> 4;
      Wt[(size_t)(n0 + nl) * Kpad + k0 + kl] = f2bf(tbuf[kl][nl]);
    }
    return;
  }

  // ---- gather part: bf16 expert_in[row][704] + fp32 softmax gates ----
  const int gb_ = bid - 4096;
  const int wid = threadIdx.x >> 6, lane = threadIdx.x & 63;
  const int rl = gb_ * 4 + wid;
  const int r = rowBase + rl;
  const int* xd = Xd + (size_t)r * 20;
  u16* er = ein + (size_t)rl * 704;
#pragma unroll
  for (int i = 0; i < 3; ++i) {                 // 20 feat x 8 subchunks = 160
    const int li = i * 64 + lane;
    if (li < 160) {
      const int f = li >> 3, sub = li & 7;
      const int idx = xd[f];
      const float4 v = *(const float4*)&deep_emb[((size_t)f * 100000 + idx) * 32 + sub * 4];
      u16x4 o;
      o.x = f2bf(v.x); o.y = f2bf(v.y); o.z = f2bf(v.z); o.w = f2bf(v.w);
      *(u16x4*)&er[f * 32 + sub * 4] = o;
    }
  }
  if (lane < 10) er[640 + lane] = f2bf(Xc[(size_t)r * 10 + lane]);
  if (lane < 54) er[650 + lane] = 0;
  if (lane < 20) gi[wid][lane] = lin_emb[(size_t)lane * 100000 + xd[lane]];
  if (lane < 10) gi[wid][20 + lane] = Xc[(size_t)r * 10 + lane];
  asm volatile("s_waitcnt lgkmcnt(0)" ::: "memory");
  float logit = 0.f;
  const int t = lane >> 3, ee = lane & 7;
  if (lane < 16) {
    float a = gb[t * 8 + ee];
#pragma unroll
    for (int i = 0; i < 30; ++i) a += gi[wid][i] * gW[(t * 30 + i) * 8 + ee];
    logit = a;
  }
  float mx = logit;
#pragma unroll
  for (int d = 1; d < 8; d <<= 1) mx = fmaxf(mx, __shfl_xor(mx, d));
  float p = expf(logit - mx);
  float sm = p;
#pragma unroll
  for (int d = 1; d < 8; d <<= 1) sm += __shfl_xor(sm, d);
  if (lane < 16) gates[(size_t)rl * 16 + lane] = p / sm;
}

// ------------------------ 128x128 2-phase GEMM -----------------------------
// C[e] = act(A[e] [M x K] * B[e]^T [N x K] + bias[e]);  K mult of 64.
// 1-D grid nCol*nRow*8, block 256 (4 waves, 64x64/wave).  Expert-per-XCD.
template<bool RELU, typename CT>
__global__ __launch_bounds__(256, 2)
void gemm_kernel(const u16* __restrict__ A, size_t sAe,
                 const u16* __restrict__ Bw, size_t sBe,
                 CT* __restrict__ C, size_t sCe, int ldc,
                 const float* __restrict__ bias, int N, int K,
                 int nCol, int nRow)
{
  __shared__ u16 As[2][8192];   // [128][64] bf16, XOR-swizzled via source
  __shared__ u16 Bs[2][8192];

  const int perE = nCol * nRow;
  const int work = (blockIdx.x & 7) * perE + (blockIdx.x >> 3); // expert/XCD
  const int e  = work / perE;
  const int rem = work - e * perE;
  const int mt = rem / nCol;
  const int ct = rem - mt * nCol;

  const u16* Ae = A + (size_t)e * sAe;
  const u16* Be = Bw + (size_t)e * sBe;
  const int row0 = mt * 128;
  const int col0 = ct * 128;
  const int tid = threadIdx.x;
  const int lane = tid & 63;
  const int wid = tid >> 6;
  const int wr = wid >> 1, wc = wid & 1;         // wave -> 64x64 quadrant

  int rw_[4], gch_[4], ldsOff_[4];
#pragma unroll
  for (int i = 0; i < 4; ++i) {
    const int o = (wid * 4 + i) * 1024 + lane * 16;   // byte off in 16KB tile
    rw_[i] = o >> 7;                                  // row 0..127
    const int ch = (o >> 4) & 7;
    gch_[i] = ch ^ (rw_[i] & 7);                      // pre-swizzled source
    ldsOff_[i] = (wid * 4 + i) * 512;                 // u16 units
  }
  const int KT = K >> 6;

  auto stage = [&](int buf, int kt) {
    const int kb = kt << 6;
#pragma unroll
    for (int i = 0; i < 4; ++i) {
      gload16(Ae + ((size_t)(row0 + rw_[i]) * K + kb + (gch_[i] << 3)),
              &As[buf][ldsOff_[i]]);
      gload16(Be + ((size_t)(col0 + rw_[i]) * K + kb + (gch_[i] << 3)),
              &Bs[buf][ldsOff_[i]]);
    }
  };

  f32x4 acc[4][4];
#pragma unroll
  for (int m = 0; m < 4; ++m)
#pragma unroll
    for (int n = 0; n < 4; ++n) acc[m][n] = {0.f, 0.f, 0.f, 0.f};

  stage(0, 0);
  __syncthreads();                               // drains vmcnt(0) too

  for (int kt = 0; kt < KT; ++kt) {
    const int cur = kt & 1;
    if (kt + 1 < KT) stage(cur ^ 1, kt + 1);     // prefetch in flight over MFMA
#pragma unroll
    for (int half = 0; half < 2; ++half) {       // k = 0..31, 32..63
      const int kp = half * 4 + (lane >> 4);
      bf16x8 af[4], bfr[4];
#pragma unroll
      for (int m = 0; m < 4; ++m) {
        const int rw = wr * 64 + m * 16 + (lane & 15);
        af[m] = *(const bf16x8*)&As[cur][rw * 64 + ((kp ^ (rw & 7)) << 3)];
      }
#pragma unroll
      for (int n = 0; n < 4; ++n) {
        const int rw = wc * 64 + n * 16 + (lane & 15);
        bfr[n] = *(const bf16x8*)&Bs[cur][rw * 64 + ((kp ^ (rw & 7)) << 3)];
      }
      __builtin_amdgcn_s_setprio(1);
#pragma unroll
      for (int m = 0; m < 4; ++m)
#pragma unroll
        for (int n = 0; n < 4; ++n)
          acc[m][n] = MFMA16(af[m], bfr[n], acc[m][n]);
      __builtin_amdgcn_s_setprio(0);
    }
    __syncthreads();
  }

  const int cl = lane & 15;
  const int rl4 = (lane >> 4) * 4;
#pragma unroll
  for (int n = 0; n < 4; ++n) {
    const int col = col0 + wc * 64 + n * 16 + cl;
    const float bv = bias[(size_t)e * N + col];
#pragma unroll
    for (int m = 0; m < 4; ++m) {
      const int grow = row0 + wr * 64 + m * 16 + rl4;
      CT* cp = C + (size_t)e * sCe + (size_t)grow * ldc + col;
#pragma unroll
      for (int j = 0; j < 4; ++j) {
        float v = acc[m][n][j] + bv;
        if (RELU) v = fmaxf(v, 0.f);
        if constexpr (sizeof(CT) == 2) cp[(size_t)j * ldc] = (CT)f2bf(v);
        else                           cp[(size_t)j * ldc] = (CT)v;
      }
    }
  }
}

// ------------------------- combine + task towers ---------------------------
__global__ __launch_bounds__(256)
void tower_kernel(const u16* __restrict__ eo,      // [8][Bc][128] bf16
                  const float* __restrict__ gates, // [Bc][2][8]
                  const float* __restrict__ tW1,   // [2][128][64]
                  const float* __restrict__ tb1, const float* __restrict__ tW2,
                  const float* __restrict__ tb2, float* __restrict__ out,
                  int rowBase, int Bc)
{
  __shared__ u16 w1s[2 * 128 * 64];
  __shared__ float tin[4][2][128];
  for (int i = threadIdx.x; i < 2 * 128 * 64; i += 256) w1s[i] = f2bf(tW1[i]);
  __syncthreads();
  const int wid = threadIdx.x >> 6, lane = threadIdx.x & 63;
  const int stride = gridDim.x * 4;
  for (int it = 0; it < 4; ++it) {
    const int r = blockIdx.x * 4 + wid + it * stride;
    const float* gp = gates + (size_t)r * 16;
    float g[16];
#pragma unroll
    for (int i = 0; i < 16; ++i) g[i] = gp[i];
    float t0a = 0.f, t0b = 0.f, t1a = 0.f, t1b = 0.f;
#pragma unroll
    for (int ee = 0; ee < 8; ++ee) {
      const u32 pv = *(const u32*)(eo + ((size_t)ee * Bc + r) * 128 + lane * 2);
      const float a = bf2f((u16)(pv & 0xffff));
      const float b = bf2f((u16)(pv >> 16));
      t0a += g[ee] * a;      t0b += g[ee] * b;
      t1a += g[8 + ee] * a;  t1b += g[8 + ee] * b;
    }
    tin[wid][0][lane * 2] = t0a; tin[wid][0][lane * 2 + 1] = t0b;
    tin[wid][1][lane * 2] = t1a; tin[wid][1][lane * 2 + 1] = t1b;
    asm volatile("s_waitcnt lgkmcnt(0)" ::: "memory");
#pragma unroll
    for (int t = 0; t < 2; ++t) {
      float acc = tb1[t * 64 + lane];
#pragma unroll 8
      for (int d = 0; d < 128; ++d)
        acc += tin[wid][t][d] * bf2f(w1s[(t * 128 + d) * 64 + lane]);
      acc = fmaxf(acc, 0.f);
      float s = acc * tW2[t * 64 + lane];
#pragma unroll
      for (int dd = 1; dd < 64; dd <<= 1) s += __shfl_xor(s, dd);
      if (lane == 0) out[(size_t)(rowBase + r) * 2 + t] = s + tb2[t];
    }
    asm volatile("s_waitcnt lgkmcnt(0)" ::: "memory");
  }
}

// ------------------------------ launch -------------------------------------
extern "C" void kernel_launch(void* const* d_in, const int* in_sizes, int n_in,
                              void* d_out, int out_size, void* d_ws, size_t ws_size,
                              hipStream_t stream) {
  const int*   X_dis   = (const int*)  d_in[0];
  const float* X_cont  = (const float*)d_in[1];
  const float* lin_emb = (const float*)d_in[2];
  const float* deep_emb= (const float*)d_in[3];
  const float* eW1     = (const float*)d_in[4];
  const float* eb1     = (const float*)d_in[5];
  const float* eW2     = (const float*)d_in[6];
  const float* eb2     = (const float*)d_in[7];
  const float* eW3     = (const float*)d_in[8];
  const float* eb3     = (const float*)d_in[9];
  const float* gW      = (const float*)d_in[10];
  const float* gb      = (const float*)d_in[11];
  const float* tW1     = (const float*)d_in[12];
  const float* tb1     = (const float*)d_in[13];
  const float* tW2     = (const float*)d_in[14];
  const float* tb2     = (const float*)d_in[15];
  float* out = (float*)d_out;

  char* ws = (char*)d_ws;
  u16* w1t = (u16*)(ws + 0);          // 8 x 512 x 704 x 2B
  u16* w2t = (u16*)(ws + 5767168);    // 8 x 256 x 512 x 2B
  u16* w3t = (u16*)(ws + 7864320);    // 8 x 128 x 256 x 2B
  const size_t base = 8388608;

  const int B = 16384;
  int NC = 1;   // per-row: ein 1408 + gates 64 + h1 8192 + h2 4096 = 13760 B
  while (NC < 64 && base + (size_t)(B / NC) * 13760ull > ws_size) NC <<= 1;
  const int Bc = B / NC;

  u16*   ein   = (u16*)  (ws + base);
  float* gates = (float*)(ws + base + (size_t)Bc * 1408);
  u16*   h1    = (u16*)  (ws + base + (size_t)Bc * 1472);
  u16*   h2    = (u16*)  (ws + base + (size_t)Bc * 1472 + (size_t)Bc * 8192);
  u16*   eo    = h1;                  // aliases h1 (dead after GEMM2)

  for (int c = 0; c < NC; ++c) {
    const int rowBase = c * Bc;
    const int nRow = Bc / 128;
    prep_kernel<<<4096 + Bc / 4, 256, 0, stream>>>(
        eW1, eW2, eW3, w1t, w2t, w3t,
        X_dis, X_cont, lin_emb, deep_emb, gW, gb, ein, gates, rowBase, Bc);
    gemm_kernel<true, u16><<<4 * nRow * 8, 256, 0, stream>>>(
        ein, 0,                 w1t, (size_t)512 * 704,
        h1, (size_t)Bc * 512, 512, eb1, 512, 704, 4, nRow);
    gemm_kernel<true, u16><<<2 * nRow * 8, 256, 0, stream>>>(
        h1, (size_t)Bc * 512,   w2t, (size_t)256 * 512,
        h2, (size_t)Bc * 256, 256, eb2, 256, 512, 2, nRow);
    gemm_kernel<false, u16><<<1 * (Bc / 128) * 8, 256, 0, stream>>>(
        h2, (size_t)Bc * 256,   w3t, (size_t)128 * 256,
        eo, (size_t)Bc * 128, 128, eb3, 128, 256, 1, Bc / 128);
    tower_kernel<<<Bc / 16, 256, 0, stream>>>(eo, gates, tW1, tb1, tW2, tb2,
                                              out, rowBase, Bc);
  }
}